// Round 1
// baseline (1093.694 us; speedup 1.0000x reference)
//
#include <hip/hip_runtime.h>
#include <math.h>

#define N_   256
#define C_   2048
#define HW_  196
#define HW4_ 49
#define K_   7

// ---------------------------------------------------------------------------
// Pass 1: per-n fused reduction over feats[n, :, :, :]
//   pooled[n, c] = mean over 196 spatial
//   amap[n, hw]  = sum over 2048 channels
// grid = N_ blocks, 512 threads (8 waves). Each wave owns channels c = w mod 8.
// ---------------------------------------------------------------------------
__global__ __launch_bounds__(512) void pass1_kernel(
    const float* __restrict__ feats,
    float* __restrict__ pooled,
    float* __restrict__ amap)
{
    const int n    = blockIdx.x;
    const int wave = threadIdx.x >> 6;
    const int lane = threadIdx.x & 63;
    const float4* f4 = (const float4*)(feats + (size_t)n * C_ * HW_);

    float a0 = 0.f, a1 = 0.f, a2 = 0.f, a3 = 0.f;  // lane's spatial accumulators

    for (int c = wave; c < C_; c += 8) {
        float4 v = make_float4(0.f, 0.f, 0.f, 0.f);
        if (lane < HW4_) v = f4[c * HW4_ + lane];
        a0 += v.x; a1 += v.y; a2 += v.z; a3 += v.w;
        float s = (v.x + v.y) + (v.z + v.w);
        #pragma unroll
        for (int off = 32; off >= 1; off >>= 1) s += __shfl_xor(s, off);
        if (lane == 0) pooled[n * C_ + c] = s * (1.0f / 196.0f);
    }

    __shared__ float ash[8][HW_];
    if (lane < HW4_) {
        ash[wave][lane * 4 + 0] = a0;
        ash[wave][lane * 4 + 1] = a1;
        ash[wave][lane * 4 + 2] = a2;
        ash[wave][lane * 4 + 3] = a3;
    }
    __syncthreads();
    const int t = threadIdx.x;
    if (t < HW_) {
        float s = 0.f;
        #pragma unroll
        for (int w = 0; w < 8; ++w) s += ash[w][t];
        amap[n * HW_ + t] = s;
    }
}

// ---------------------------------------------------------------------------
// Centroid spatial maps: kmap[k, hw] = sum_c centroids[k, c, hw]
// grid = K_ blocks, 64 threads (lane < 49 active, float4 per lane)
// ---------------------------------------------------------------------------
__global__ __launch_bounds__(64) void kmap_kernel(
    const float* __restrict__ cent,
    float* __restrict__ kmap)
{
    const int k    = blockIdx.x;
    const int lane = threadIdx.x;
    if (lane >= HW4_) return;
    const float4* c4 = (const float4*)(cent + (size_t)k * C_ * HW_);
    float4 acc = make_float4(0.f, 0.f, 0.f, 0.f);
    for (int c = 0; c < C_; ++c) {
        float4 v = c4[c * HW4_ + lane];
        acc.x += v.x; acc.y += v.y; acc.z += v.z; acc.w += v.w;
    }
    ((float4*)kmap)[k * HW4_ + lane] = acc;
}

// ---------------------------------------------------------------------------
// labels[n] = argmin_k sum_hw |amap[n,hw] - kmap[k,hw]|
// grid = N_ blocks of one wave
// ---------------------------------------------------------------------------
__global__ __launch_bounds__(64) void label_kernel(
    const float* __restrict__ amap,
    const float* __restrict__ kmap,
    int* __restrict__ labels)
{
    const int n    = blockIdx.x;
    const int lane = threadIdx.x;
    float4 av = make_float4(0.f, 0.f, 0.f, 0.f);
    if (lane < HW4_) av = ((const float4*)amap)[n * HW4_ + lane];
    float best = 3.4e38f;
    int bestk = 0;
    for (int k = 0; k < K_; ++k) {
        float4 kv = make_float4(0.f, 0.f, 0.f, 0.f);
        if (lane < HW4_) kv = ((const float4*)kmap)[k * HW4_ + lane];
        float d = fabsf(av.x - kv.x) + fabsf(av.y - kv.y) +
                  fabsf(av.z - kv.z) + fabsf(av.w - kv.w);
        #pragma unroll
        for (int off = 32; off >= 1; off >>= 1) d += __shfl_xor(d, off);
        if (d < best) { best = d; bestk = k; }   // strict < keeps first (argmin tie rule)
    }
    if (lane == 0) labels[n] = bestk;
}

// ---------------------------------------------------------------------------
// Selector GEMM: sel[n, c] = tanh(b[c] + sum_j pooled[n,j] * W[c,j])
// A = pooled [256 x 2048] row-major, B = W [2048 x 2048] row-major (NT GEMM)
// tile 32(M) x 64(N), BK=16, 256 threads, 2x4 micro-tile
// grid = (2048/64, 256/32) = (32, 8) = 256 blocks
// ---------------------------------------------------------------------------
#define TM 32
#define TN 64
#define BK 16

__global__ __launch_bounds__(256) void selector_gemm_kernel(
    const float* __restrict__ A,
    const float* __restrict__ W,
    const float* __restrict__ bias,
    float* __restrict__ sel)
{
    __shared__ float As[BK][TM + 2];   // +2 pad: keep float2 alignment, break conflicts
    __shared__ float Bs[BK][TN + 4];   // +4 pad: keep float4 alignment

    const int tid = threadIdx.x;
    const int m0 = blockIdx.y * TM;
    const int n0 = blockIdx.x * TN;
    const int tx = tid & 15;   // col group: 4 cols
    const int ty = tid >> 4;   // row group: 2 rows

    float acc[2][4] = {{0.f, 0.f, 0.f, 0.f}, {0.f, 0.f, 0.f, 0.f}};

    const int lkk = tid & 15;
    const int lr  = tid >> 4;  // 0..15

    for (int k0 = 0; k0 < C_; k0 += BK) {
        #pragma unroll
        for (int rr = 0; rr < 2; ++rr) {
            int row = lr + rr * 16;
            As[lkk][row] = A[(size_t)(m0 + row) * C_ + k0 + lkk];
        }
        #pragma unroll
        for (int rr = 0; rr < 4; ++rr) {
            int row = lr + rr * 16;
            Bs[lkk][row] = W[(size_t)(n0 + row) * C_ + k0 + lkk];
        }
        __syncthreads();
        #pragma unroll
        for (int k = 0; k < BK; ++k) {
            float a0 = As[k][2 * ty];
            float a1 = As[k][2 * ty + 1];
            float b0 = Bs[k][4 * tx + 0];
            float b1 = Bs[k][4 * tx + 1];
            float b2 = Bs[k][4 * tx + 2];
            float b3 = Bs[k][4 * tx + 3];
            acc[0][0] += a0 * b0; acc[0][1] += a0 * b1; acc[0][2] += a0 * b2; acc[0][3] += a0 * b3;
            acc[1][0] += a1 * b0; acc[1][1] += a1 * b1; acc[1][2] += a1 * b2; acc[1][3] += a1 * b3;
        }
        __syncthreads();
    }

    #pragma unroll
    for (int i = 0; i < 2; ++i) {
        int row = m0 + 2 * ty + i;
        #pragma unroll
        for (int j = 0; j < 4; ++j) {
            int col = n0 + 4 * tx + j;
            sel[(size_t)row * C_ + col] = tanhf(acc[i][j] + bias[col]);
        }
    }
}

// ---------------------------------------------------------------------------
// Final: out[n,c,hw] = feats[n,c,hw] + sel[n,c] * centroids[labels[n],c,hw]
// float4 granularity: per n there are 2048*49 = 100352 float4 -> 392 blocks x 256
// ---------------------------------------------------------------------------
__global__ __launch_bounds__(256) void out_kernel(
    const float* __restrict__ feats,
    const float* __restrict__ cent,
    const float* __restrict__ sel,
    const int* __restrict__ labels,
    float* __restrict__ out)
{
    const int n    = blockIdx.y;
    const int idx4 = blockIdx.x * 256 + threadIdx.x;  // 0 .. 100351
    const int c    = idx4 / HW4_;
    const int lab  = labels[n];
    const float s  = sel[n * C_ + c];

    const size_t off  = (size_t)n * (C_ * HW4_) + idx4;
    const size_t moff = (size_t)lab * (C_ * HW4_) + idx4;
    float4 f = ((const float4*)feats)[off];
    float4 m = ((const float4*)cent)[moff];
    float4 o;
    o.x = f.x + s * m.x;
    o.y = f.y + s * m.y;
    o.z = f.z + s * m.z;
    o.w = f.w + s * m.w;
    ((float4*)out)[off] = o;
}

// ---------------------------------------------------------------------------
extern "C" void kernel_launch(void* const* d_in, const int* in_sizes, int n_in,
                              void* d_out, int out_size, void* d_ws, size_t ws_size,
                              hipStream_t stream) {
    const float* feats = (const float*)d_in[0];   // [256, 2048, 14, 14]
    const float* cent  = (const float*)d_in[1];   // [7, 2048, 14, 14]
    const float* W_sel = (const float*)d_in[2];   // [2048, 2048]
    const float* b_sel = (const float*)d_in[3];   // [2048]
    float* out = (float*)d_out;

    // workspace layout (floats)
    float* ws     = (float*)d_ws;
    float* pooled = ws;                          // 256*2048       = 524288
    float* amap   = pooled + (size_t)N_ * C_;    // 256*196        = 50176
    float* kmap   = amap + (size_t)N_ * HW_;     // 7*196          = 1372
    float* sel    = kmap + (size_t)K_ * HW_;     // 256*2048       = 524288
    int*   labels = (int*)(sel + (size_t)N_ * C_); // 256

    pass1_kernel<<<dim3(N_), dim3(512), 0, stream>>>(feats, pooled, amap);
    kmap_kernel<<<dim3(K_), dim3(64), 0, stream>>>(cent, kmap);
    label_kernel<<<dim3(N_), dim3(64), 0, stream>>>(amap, kmap, labels);
    selector_gemm_kernel<<<dim3(C_ / TN, N_ / TM), dim3(256), 0, stream>>>(
        pooled, W_sel, b_sel, sel);
    out_kernel<<<dim3((C_ * HW4_) / 256, N_), dim3(256), 0, stream>>>(
        feats, cent, sel, labels, out);
}